// Round 10
// baseline (93.328 us; speedup 1.0000x reference)
//
#include <hip/hip_runtime.h>
#include <math.h>

// LDDMM variational RHS, Gaussian kernel sigma=0.1, B=1, N=8192, D=3.
// out[0:N*3]     = dmom_i = 100 * (x_i * sum_j W_ij - sum_j W_ij x_j)
// out[N*3:2*N*3] = dcp_i  = sum_j K_ij p_j
// K_ij = exp(-|x_i-x_j|^2/(2 sig^2)), W_ij = K_ij*(p_i.p_j), p=clamp(mom,-1,1)
//
// R16: R15 passed 88.5 (best) but partial is still ~35us vs ~10us model --
// a persistent ~3x factor on EVERY variant, unattributable because the
// partial hides below five ~43us fills in top-5. This kernel is both the
// best-model design and self-diagnosing: ONE plain dispatch (R14 proved a
// single kernel passes AND, if slow, outranks fills -> full counters).
// Design: j-packed v2f (no per-iter splats; j-operands are natural 64-bit
// pairs from ds_read_b128; i-side splats hoisted), NI=4 i/thread (4x LDS
// amortization), 128 j-slices at stride 272B (=16 mod 128 -> the 16
// concurrent half-wave addresses alias 2-per-bank-quad = free, m136),
// grid 1024x256, 8 chunk rounds of 1024 j (34.8KB LDS), endgame =
// shfl_xor{2,4,8,16,32} + 1.8KB LDS wave-combine, 8 threads write outputs
// once. No ws/atomics/memset. Model: VALU 6.4 + LDS 5 + exp 2-7 + tails
// ~= 12-18us. Predict: dur 60-67 (kernel hidden = success). If factor
// persists: kernel 30-45us, visible in top-5 WITH counters -> next round
// is counter-driven.

#define NPTS    8192
#define N3      (NPTS * 3)
#define THREADS 256
#define NI      4                     // i's per thread
#define ITH     2                     // i-threads per block (t&1)
#define IPB     (NI * ITH)            // 8 i's per block
#define NBLK    (NPTS / IPB)          // 1024 blocks
#define NSL     128                   // j-slices (s = t>>1)
#define CHUNK   1024                  // j's staged per round
#define NCHUNK  (NPTS / CHUNK)        // 8 rounds
#define JPS     (CHUNK / 2 / NSL)     // 4 j-pairs per slice per round
#define STR4    (JPS * 4 + 1)         // 17 float4 = 272 B slice stride

// exp(-d2/(2*0.1^2)) = exp2(d2 * (-50*log2(e)))
#define COEF    (-72.134752044448170f)
#define M2COEF  (144.269504088896340f)     // -2*COEF
#define UNSC100 (0.69314718055994531f)     // 100 / M2COEF

typedef float v2f __attribute__((ext_vector_type(2)));

__device__ __forceinline__ v2f vsplat(float s) { v2f r; r.x = s; r.y = s; return r; }

__device__ __forceinline__ v2f pkfma(v2f a, v2f b, v2f c) {
#if __has_builtin(__builtin_elementwise_fma)
    return __builtin_elementwise_fma(a, b, c);
#else
    v2f r; r.x = fmaf(a.x, b.x, c.x); r.y = fmaf(a.y, b.y, c.y); return r;
#endif
}

__device__ __forceinline__ float fast_exp2(float x) {
#if __has_builtin(__builtin_amdgcn_exp2f)
    return __builtin_amdgcn_exp2f(x);
#else
    return exp2f(x);
#endif
}

__device__ __forceinline__ float clamp1(float v) {
    return fminf(fmaxf(v, -1.0f), 1.0f);
}

// LDS j-pair entry (4 float4 = 64B):
//  [0] = {M2*x0(j0), M2*x0(j1), M2*x1(j0), M2*x1(j1)}
//  [1] = {M2*x2(j0), M2*x2(j1), cj(j0),    cj(j1)}      cj = COEF*|xj|^2
//  [2] = {p0(j0),    p0(j1),    p1(j0),    p1(j1)}
//  [3] = {p2(j0),    p2(j1),    0,         0}
// Chunk-global pair P (0..511): slice ss=P>>2, pp=P&3 ->
//   shj[ss*STR4 + pp*4 + row];  j0 = c*CHUNK + ss*(2*JPS) + pp*2.
__global__ __launch_bounds__(THREADS, 2) void lddmm_one(const float* __restrict__ mom,
                                                        const float* __restrict__ cp,
                                                        float* __restrict__ out) {
    const int t  = (int)threadIdx.x;
    const int it = t & 1;                // i-thread 0/1
    const int s  = t >> 1;               // j-slice 0..127
    const int ibase = (int)blockIdx.x * IPB + it * NI;

    __shared__ float4 shj[NSL * STR4];   // 34816 B

    // i-side state: loop-invariant splats (NI i's, hoisted).
    v2f sx0[NI], sx1[NI], sx2[NI], sci[NI], sp0[NI], sp1[NI], sp2[NI];
#pragma unroll
    for (int n = 0; n < NI; ++n) {
        const int i = ibase + n;
        const float x0 = cp[i * 3 + 0], x1 = cp[i * 3 + 1], x2 = cp[i * 3 + 2];
        sx0[n] = vsplat(x0);
        sx1[n] = vsplat(x1);
        sx2[n] = vsplat(x2);
        sci[n] = vsplat(COEF * (x0 * x0 + x1 * x1 + x2 * x2));
        sp0[n] = vsplat(clamp1(mom[i * 3 + 0]));
        sp1[n] = vsplat(clamp1(mom[i * 3 + 1]));
        sp2[n] = vsplat(clamp1(mom[i * 3 + 2]));
    }

    v2f dcp0[NI], dcp1[NI], dcp2[NI], wsum[NI], wx0[NI], wx1[NI], wx2[NI];
#pragma unroll
    for (int n = 0; n < NI; ++n) {
        dcp0[n] = vsplat(0.f); dcp1[n] = vsplat(0.f); dcp2[n] = vsplat(0.f);
        wsum[n] = vsplat(0.f);
        wx0[n] = vsplat(0.f); wx1[n] = vsplat(0.f); wx2[n] = vsplat(0.f);
    }

    const int rbase = s * STR4;

    for (int c = 0; c < NCHUNK; ++c) {
        __syncthreads();                 // prior round's reads complete
        // ---- stage: thread t writes chunk-pairs P = 2t, 2t+1 ----
#pragma unroll
        for (int q = 0; q < 2; ++q) {
            const int P   = 2 * t + q;
            const int off = (P >> 2) * STR4 + (P & 3) * 4;
            const int j0  = c * CHUNK + (P >> 2) * (2 * JPS) + (P & 3) * 2;
            const int j1  = j0 + 1;
            const float xa0 = cp[j0 * 3 + 0], xa1 = cp[j0 * 3 + 1], xa2 = cp[j0 * 3 + 2];
            const float xb0 = cp[j1 * 3 + 0], xb1 = cp[j1 * 3 + 1], xb2 = cp[j1 * 3 + 2];
            shj[off + 0] = make_float4(M2COEF * xa0, M2COEF * xb0,
                                       M2COEF * xa1, M2COEF * xb1);
            shj[off + 1] = make_float4(M2COEF * xa2, M2COEF * xb2,
                                       COEF * (xa0 * xa0 + xa1 * xa1 + xa2 * xa2),
                                       COEF * (xb0 * xb0 + xb1 * xb1 + xb2 * xb2));
            shj[off + 2] = make_float4(clamp1(mom[j0 * 3 + 0]), clamp1(mom[j1 * 3 + 0]),
                                       clamp1(mom[j0 * 3 + 1]), clamp1(mom[j1 * 3 + 1]));
            shj[off + 3] = make_float4(clamp1(mom[j0 * 3 + 2]), clamp1(mom[j1 * 3 + 2]),
                                       0.0f, 0.0f);
        }
        __syncthreads();

        // ---- compute: this thread's JPS=4 pairs of slice s ----
#pragma unroll
        for (int p = 0; p < JPS; ++p) {
            const float4 A = shj[rbase + p * 4 + 0];
            const float4 B = shj[rbase + p * 4 + 1];
            const float4 C = shj[rbase + p * 4 + 2];
            const float4 D = shj[rbase + p * 4 + 3];
            v2f xj0p; xj0p.x = A.x; xj0p.y = A.y;
            v2f xj1p; xj1p.x = A.z; xj1p.y = A.w;
            v2f xj2p; xj2p.x = B.x; xj2p.y = B.y;
            v2f cjp;  cjp.x  = B.z; cjp.y  = B.w;
            v2f pj0p; pj0p.x = C.x; pj0p.y = C.y;
            v2f pj1p; pj1p.x = C.z; pj1p.y = C.w;
            v2f pj2p; pj2p.x = D.x; pj2p.y = D.y;
#pragma unroll
            for (int n = 0; n < NI; ++n) {
                // arg = ci + cj + xi.(M2*xj) = COEF*d2 (packed over 2 j's)
                v2f arg = sci[n] + cjp;
                arg = pkfma(sx0[n], xj0p, arg);
                arg = pkfma(sx1[n], xj1p, arg);
                arg = pkfma(sx2[n], xj2p, arg);
                v2f K;
                K.x = fast_exp2(arg.x);
                K.y = fast_exp2(arg.y);
                v2f pd = sp0[n] * pj0p;
                pd = pkfma(sp1[n], pj1p, pd);
                pd = pkfma(sp2[n], pj2p, pd);
                const v2f W = K * pd;
                dcp0[n] = pkfma(K, pj0p, dcp0[n]);
                dcp1[n] = pkfma(K, pj1p, dcp1[n]);
                dcp2[n] = pkfma(K, pj2p, dcp2[n]);
                wsum[n] = wsum[n] + W;
                wx0[n] = pkfma(W, xj0p, wx0[n]);   // M2COEF-scaled
                wx1[n] = pkfma(W, xj1p, wx1[n]);
                wx2[n] = pkfma(W, xj2p, wx2[n]);
            }
        }
    }

    // ---- fold v2f halves -> r[n][7]; reduce over the 32 same-i lanes of
    // this wave (lanes it, it+2, ..., it+62): xor masks 2,4,8,16,32 ----
    float r[NI][7];
#pragma unroll
    for (int n = 0; n < NI; ++n) {
        r[n][0] = dcp0[n].x + dcp0[n].y;
        r[n][1] = dcp1[n].x + dcp1[n].y;
        r[n][2] = dcp2[n].x + dcp2[n].y;
        r[n][3] = wsum[n].x + wsum[n].y;
        r[n][4] = wx0[n].x + wx0[n].y;
        r[n][5] = wx1[n].x + wx1[n].y;
        r[n][6] = wx2[n].x + wx2[n].y;
    }
#pragma unroll
    for (int m = 2; m <= 32; m <<= 1) {
#pragma unroll
        for (int n = 0; n < NI; ++n) {
#pragma unroll
            for (int v = 0; v < 7; ++v) {
                r[n][v] += __shfl_xor(r[n][v], m);
            }
        }
    }

    // ---- combine 4 wave-partials via reused LDS; 8 threads write out ----
    __syncthreads();                     // all compute reads of shj done
    float* rb = (float*)shj;             // 4 waves x 8 i x 7 = 224 floats
    const int wave = t >> 6;
    if ((t & 63) < 2) {                  // lane it of each wave holds sums
#pragma unroll
        for (int n = 0; n < NI; ++n) {
#pragma unroll
            for (int v = 0; v < 7; ++v) {
                rb[wave * (IPB * 7) + ((t & 1) * NI + n) * 7 + v] = r[n][v];
            }
        }
    }
    __syncthreads();
    if (t < IPB) {
        float f[7];
#pragma unroll
        for (int v = 0; v < 7; ++v) {
            f[v] = rb[0 * (IPB * 7) + t * 7 + v] + rb[1 * (IPB * 7) + t * 7 + v]
                 + rb[2 * (IPB * 7) + t * 7 + v] + rb[3 * (IPB * 7) + t * 7 + v];
        }
        const int i = (int)blockIdx.x * IPB + t;
        const float x0 = cp[i * 3 + 0], x1 = cp[i * 3 + 1], x2 = cp[i * 3 + 2];
        out[N3 + i * 3 + 0] = f[0];
        out[N3 + i * 3 + 1] = f[1];
        out[N3 + i * 3 + 2] = f[2];
        // dmom = 100*xi*wsum - (100/M2COEF)*wxs
        out[i * 3 + 0] = fmaf(100.0f * x0, f[3], -UNSC100 * f[4]);
        out[i * 3 + 1] = fmaf(100.0f * x1, f[3], -UNSC100 * f[5]);
        out[i * 3 + 2] = fmaf(100.0f * x2, f[3], -UNSC100 * f[6]);
    }
}

extern "C" void kernel_launch(void* const* d_in, const int* in_sizes, int n_in,
                              void* d_out, int out_size, void* d_ws, size_t ws_size,
                              hipStream_t stream) {
    const float* mom = (const float*)d_in[0];
    const float* cp  = (const float*)d_in[1];
    float* out = (float*)d_out;

    (void)d_ws; (void)ws_size;  // single self-contained dispatch
    hipLaunchKernelGGL(lddmm_one, dim3(NBLK), dim3(THREADS), 0, stream, mom, cp, out);
}